// Round 6
// baseline (348.708 us; speedup 1.0000x reference)
//
#include <hip/hip_runtime.h>
#include <math.h>

#define NCH   2048      // B*C = 32*64
#define TLEN  16384
#define NSEG  255
#define NF    65

// ---------------- Kernel A: Welch PSD accumulation ----------------
// element-level XOR swizzle: segment bases are 64-float strided -> without this,
// every per-thread FFT load is a 64-way LDS bank conflict.
__device__ __forceinline__ int swzA(int i) {
    return (i & ~63) | ((i & 63) ^ ((i >> 6) & 31));
}
__host__ __device__ constexpr int br6(int i) {
    return ((i & 1) << 5) | ((i & 2) << 3) | ((i & 4) << 1) |
           ((i & 8) >> 1) | ((i & 16) >> 3) | ((i & 32) >> 5);
}

// waves_per_eu(2,2): pin BOTH min and max (R3: min-only still spilled).
// LDS=64KiB caps residency at 2 blocks/CU anyway, so max=2 costs nothing
// and raises the effective VGPR budget to 256 -> ~170 live fits.
__attribute__((amdgpu_flat_work_group_size(256, 256), amdgpu_waves_per_eu(2, 2)))
__global__ void psd_kernel(const float* __restrict__ x, float* __restrict__ psd_g) {
    __shared__ float xl[TLEN];                 // exactly 64 KiB
    const int ch  = blockIdx.x;
    const int tid = threadIdx.x;
    const float4* __restrict__ x4 = reinterpret_cast<const float4*>(x) + (size_t)ch * (TLEN / 4);
#pragma unroll
    for (int it = 0; it < 16; ++it) {
        int i4 = it * 256 + tid;
        float4 v = x4[i4];
        int i = i4 << 2;
        xl[swzA(i + 0)] = v.x;
        xl[swzA(i + 1)] = v.y;
        xl[swzA(i + 2)] = v.z;
        xl[swzA(i + 3)] = v.w;
    }
    __syncthreads();

    // one thread = one 128-sample segment (50% overlap). Per-segment mean
    // subtraction only affects DFT bin 0 (handled via constant D0 downstream),
    // so we skip it entirely.
    const int   seg   = (tid < NSEG) ? tid : (NSEG - 1);
    const float valid = (tid < NSEG) ? 1.0f : 0.0f;
    const int   base  = seg * 64;

    // pack reals into 64 complex, bit-reversed for DIT
    float zr[64], zi[64];
#pragma unroll
    for (int i = 0; i < 64; ++i) {
        const int rb = br6(i);
        zr[i] = xl[swzA(base + 2 * rb)];
        zi[i] = xl[swzA(base + 2 * rb + 1)];
    }

    // 64-pt complex FFT, fully unrolled; twiddle recurrence starts from
    // literals and is fully constant-folded (zero runtime cost).
    constexpr float STR[6] = {-1.0f, 0.0f, 0.70710678f, 0.92387953f, 0.98078528f, 0.99518473f};
    constexpr float STI[6] = {0.0f, -1.0f, -0.70710678f, -0.38268343f, -0.19509032f, -0.09801714f};
#pragma unroll
    for (int st = 0; st < 6; ++st) {
        const int m = 1 << st;
        float wr = 1.0f, wi = 0.0f;
#pragma unroll
        for (int j = 0; j < m; ++j) {
#pragma unroll
            for (int k = 0; k < 64; k += 2 * m) {
                const int a = k + j, b = a + m;
                float tr = wr * zr[b] - wi * zi[b];
                float ti = wr * zi[b] + wi * zr[b];
                zr[b] = zr[a] - tr; zi[b] = zi[a] - ti;
                zr[a] += tr;        zi[a] += ti;
            }
            float nwr = wr * STR[st] - wi * STI[st];
            wi = wr * STI[st] + wi * STR[st];
            wr = nwr;
        }
    }

    // untangle real-FFT bins into vals[0..63] (+p64); scale + validity mask
    float vals[64];
    float p64;
    const float INV128 = 1.0f / 128.0f;
    {
        float v0 = zr[0] + zi[0];                       // X[0] (overridden via D0 later)
        vals[0] = v0 * v0 * INV128 * valid;
        float v1 = zr[0] - zi[0];                       // X[64]
        p64 = v1 * v1 * INV128 * valid;
        vals[32] = (zr[32] * zr[32] + zi[32] * zi[32]) * (2.0f * INV128) * valid;
    }
    float Wr = 0.9987954562f, Wi = -0.0490676743f;
#pragma unroll
    for (int k = 1; k < 32; ++k) {
        float ar = 0.5f * (zr[k] + zr[64 - k]);
        float ai = 0.5f * (zi[k] - zi[64 - k]);
        float br_ = 0.5f * (zi[k] + zi[64 - k]);
        float bi_ = 0.5f * (zr[64 - k] - zr[k]);
        float tr = Wr * br_ - Wi * bi_;
        float ti = Wr * bi_ + Wi * br_;
        float e1r = ar + tr, e1i = ai + ti;             // X[k]
        float e2r = ar - tr, e2i = ai - ti;             // conj(X[64-k])
        vals[k]      = (e1r * e1r + e1i * e1i) * (2.0f * INV128) * valid;
        vals[64 - k] = (e2r * e2r + e2i * e2i) * (2.0f * INV128) * valid;
        float nWr = Wr * 0.9987954562f - Wi * (-0.0490676743f);
        Wi = Wr * (-0.0490676743f) + Wi * 0.9987954562f;
        Wr = nWr;
    }

    // Butterfly transpose-reduce: 64 bins x 64 lanes in 63 shfls (vs 390 for
    // per-bin 6-level reduces). All slot indices compile-time (rule #20);
    // lane-dependent choice is on VALUES via predication.
    const int lane = tid & 63;
#define RSTAGE(m)                                                    \
    {                                                                \
        const bool hi = (lane & (m)) != 0;                           \
        _Pragma("unroll")                                            \
        for (int j = 0; j < (m); ++j) {                              \
            float a = vals[j], b = vals[j + (m)];                    \
            float t = __shfl_xor(hi ? a : b, (m));                   \
            vals[j] = (hi ? b : a) + t;                              \
        }                                                            \
    }
    RSTAGE(32) RSTAGE(16) RSTAGE(8) RSTAGE(4) RSTAGE(2) RSTAGE(1)
#undef RSTAGE
    p64 += __shfl_xor(p64, 32);
    p64 += __shfl_xor(p64, 16);
    p64 += __shfl_xor(p64, 8);
    p64 += __shfl_xor(p64, 4);
    p64 += __shfl_xor(p64, 2);
    p64 += __shfl_xor(p64, 1);

    float* pg = psd_g + ch * NF;
    atomicAdd(&pg[lane], vals[0]);                      // one atomic per lane
    if (lane == 0) atomicAdd(&pg[64], p64);
}

// ---------------- Kernel B1: sqrt(psd) + barycenter sum over b ----------------
__launch_bounds__(256)
__global__ void sqrtp_kernel(const float* __restrict__ psd_g, float* __restrict__ sqrtP,
                             float* __restrict__ S) {
    int id = blockIdx.x * 256 + threadIdx.x;
    if (id >= 64 * NF) return;
    int c = id / NF, f = id - c * NF;
    float sum = 0.0f;
    for (int b = 0; b < 32; ++b) {
        int ch = (b << 6) + c;
        float sp = sqrtf(psd_g[ch * NF + f] * (1.0f / 255.0f));   // mean over 255 segs
        sqrtP[ch * NF + f] = sp;
        sum += sp;
    }
    S[id] = sum * (1.0f / 65.0f);
}

// ---------------- Kernel B2: D -> h (irfft) -> conv-layout filter ----------------
__launch_bounds__(128)
__global__ void filt_kernel(const float* __restrict__ sqrtP, const float* __restrict__ S,
                            float* __restrict__ h2g) {
    __shared__ float Dl[NF];
    const int ch = blockIdx.x;
    const int c  = ch & 63;
    const int n  = threadIdx.x;
    if (n < NF) {
        if (n == 0) {
            // bin 0 of psd is pure rounding noise in the reference; its D ratio
            // concentrates at 32/65 (255-segment averaging) -> pin it.
            Dl[0] = 32.0f / 65.0f;
        } else {
            float sp = sqrtP[ch * NF + n];
            float sv = S[c * NF + n];
            Dl[n] = (sp > 0.0f) ? sv / sp : 0.0f;
        }
    }
    __syncthreads();
    // h[n] = (1/128)(D0 + 2*sum_{f=1..63} Df cos(2pi f n/128) + D64*(-1)^n)
    float sum = Dl[0] + ((n & 1) ? -Dl[64] : Dl[64]);
#pragma unroll
    for (int f = 1; f < 64; ++f) {
        int m = (f * n) & 127;
        sum += 2.0f * Dl[f] * cosf((float)m * 0.04908738521f);
    }
    float h = sum * (1.0f / 128.0f);
    // fftshift+flip+correlation collapses (h even) to H2[k] = h[(k-63) mod 128]
    h2g[ch * 128 + ((n + 63) & 127)] = h;
}

// ---------------- Kernel C: depthwise 128-tap FIR ----------------
#define CTILE 4096
#define CHALO 160
#define XTN   (CTILE + CHALO)

__device__ __forceinline__ int swz4(int j) { return j ^ ((j >> 3) & 7); }  // float4-granular

// waves_per_eu(4,4): R4 evidence: default bounds -> compiler targeted 8
// waves/EU, architected VGPR_Count=32 for a ~45-live-reg kernel -> acc/xw
// arrays overflowed to AGPR shuffle traffic (dur 132us vs 55us FMA floor,
// VALUBusy only 71%). Pin 4 waves/EU -> 128-VGPR budget, working set fits.
// LDS 17.9KB x 4 blocks/CU = 72KB < 160KB, so residency is not LDS-limited.
__attribute__((amdgpu_flat_work_group_size(256, 256), amdgpu_waves_per_eu(4, 4)))
__global__ void conv_kernel(const float* __restrict__ x, const float* __restrict__ h2g,
                            float* __restrict__ out) {
    __shared__ __align__(16) float xt[XTN];
    __shared__ __align__(16) float H3[136];   // H3[0]=0, H3[1..128]=h2[0..127], tail 0
    const int bid = blockIdx.x;
    const int ch  = bid >> 2;
    const int t0  = (bid & 3) * CTILE;
    const int tid = threadIdx.x;
    const float* __restrict__ xrow = x + (size_t)ch * TLEN;
    for (int i = tid; i < XTN; i += 256) {
        int src = t0 - 64 + i;
        float v = (src >= 0 && src < TLEN) ? xrow[src] : 0.0f;
        int j = i >> 2;
        xt[(swz4(j) << 2) | (i & 3)] = v;
    }
    if (tid < 136) {
        H3[tid] = (tid >= 1 && tid <= 128) ? h2g[ch * 128 + tid - 1] : 0.0f;
    }
    __syncthreads();

    // 16 consecutive outputs per thread; 20-float circular register window,
    // one swizzled ds_read_b128 per 4 taps.
    float acc[16];
#pragma unroll
    for (int j = 0; j < 16; ++j) acc[j] = 0.0f;
    float xw[20];
    const float4* xt4 = reinterpret_cast<const float4*>(xt);
    const float4* H34 = reinterpret_cast<const float4*>(H3);
    const int jb = tid << 2;                 // f4 base = (16*tid)/4
#pragma unroll
    for (int c = 0; c < 5; ++c) {
        float4 v = xt4[swz4(jb + c)];
        xw[4 * c + 0] = v.x; xw[4 * c + 1] = v.y; xw[4 * c + 2] = v.z; xw[4 * c + 3] = v.w;
    }
#pragma unroll
    for (int cb = 0; cb < 33; ++cb) {
        const int kb = 4 * cb;
        float4 hv = H34[cb];                 // uniform -> LDS broadcast
#pragma unroll
        for (int dk = 0; dk < 4; ++dk) {
            const float h = (dk == 0) ? hv.x : (dk == 1) ? hv.y : (dk == 2) ? hv.z : hv.w;
#pragma unroll
            for (int j = 0; j < 16; ++j) {
                acc[j] = fmaf(xw[(kb + dk + j) % 20], h, acc[j]);
            }
        }
        if (cb < 32) {                        // slide window by 4
            float4 v = xt4[swz4(jb + cb + 5)];
            xw[(4 * cb + 0) % 20] = v.x;
            xw[(4 * cb + 1) % 20] = v.y;
            xw[(4 * cb + 2) % 20] = v.z;
            xw[(4 * cb + 3) % 20] = v.w;
        }
    }
    float4* o4 = reinterpret_cast<float4*>(out + (size_t)ch * TLEN + t0 + (tid << 4));
#pragma unroll
    for (int q = 0; q < 4; ++q) {
        o4[q] = make_float4(acc[4 * q + 0], acc[4 * q + 1], acc[4 * q + 2], acc[4 * q + 3]);
    }
}

// ---------------- host launcher ----------------
extern "C" void kernel_launch(void* const* d_in, const int* in_sizes, int n_in,
                              void* d_out, int out_size, void* d_ws, size_t ws_size,
                              hipStream_t stream) {
    (void)in_sizes; (void)n_in; (void)out_size; (void)ws_size;
    const float* x = (const float*)d_in[0];
    float* out = (float*)d_out;
    char* ws = (char*)d_ws;
    float* psd_g = (float*)(ws);                 // 2048*65 f32 = 532480 B
    float* sqrtP = (float*)(ws + 532480);        // 2048*65 f32
    float* S     = (float*)(ws + 1064960);       // 64*65 f32 = 16640 B
    float* h2g   = (float*)(ws + 1081600);       // 2048*128 f32 = 1 MiB

    hipMemsetAsync(psd_g, 0, 532480, stream);    // ws is poisoned 0xAA each call
    psd_kernel <<<NCH,     256, 0, stream>>>(x, psd_g);
    sqrtp_kernel<<<17,     256, 0, stream>>>(psd_g, sqrtP, S);
    filt_kernel<<<NCH,     128, 0, stream>>>(sqrtP, S, h2g);
    conv_kernel<<<NCH * 4, 256, 0, stream>>>(x, h2g, out);
}

// Round 9
// 292.559 us; speedup vs baseline: 1.1919x; 1.1919x over previous
//
#include <hip/hip_runtime.h>
#include <math.h>

#define NCH   2048      // B*C = 32*64
#define TLEN  16384
#define NSEG  255
#define NF    65

typedef __attribute__((ext_vector_type(8))) short bf16x8;
typedef __attribute__((ext_vector_type(4))) float f32x4;

__device__ __forceinline__ unsigned short f2bf(float f) {   // RTNE f32->bf16
    union { float f; unsigned u; } v; v.f = f;
    unsigned r = v.u + 0x7FFF + ((v.u >> 16) & 1);
    return (unsigned short)(r >> 16);
}
__device__ __forceinline__ float bf2f(unsigned short b) {
    union { unsigned u; float f; } v; v.u = ((unsigned)b) << 16;
    return v.f;
}

// ---------------- Kernel A: Welch PSD accumulation ----------------
// element-level XOR swizzle: segment bases are 64-float strided -> without this,
// every per-thread FFT load is a 64-way LDS bank conflict.
__device__ __forceinline__ int swzA(int i) {
    return (i & ~63) | ((i & 63) ^ ((i >> 6) & 31));
}
__host__ __device__ constexpr int br6(int i) {
    return ((i & 1) << 5) | ((i & 2) << 3) | ((i & 4) << 1) |
           ((i & 8) >> 1) | ((i & 16) >> 3) | ((i & 32) >> 5);
}

// waves_per_eu(2,2): pin BOTH min and max (R3: min-only still spilled).
// LDS=64KiB caps residency at 2 blocks/CU anyway, so max=2 costs nothing.
__attribute__((amdgpu_flat_work_group_size(256, 256), amdgpu_waves_per_eu(2, 2)))
__global__ void psd_kernel(const float* __restrict__ x, float* __restrict__ psd_g) {
    __shared__ float xl[TLEN];                 // exactly 64 KiB
    const int ch  = blockIdx.x;
    const int tid = threadIdx.x;
    const int lane = tid & 63;
    const int w    = tid >> 6;
    const float4* __restrict__ x4 = reinterpret_cast<const float4*>(x) + (size_t)ch * (TLEN / 4);
#pragma unroll
    for (int it = 0; it < 16; ++it) {
        int i4 = it * 256 + tid;
        float4 v = x4[i4];
        int i = i4 << 2;
        xl[swzA(i + 0)] = v.x;
        xl[swzA(i + 1)] = v.y;
        xl[swzA(i + 2)] = v.z;
        xl[swzA(i + 3)] = v.w;
    }
    __syncthreads();

    // one thread = one 128-sample segment (50% overlap). Per-segment mean
    // subtraction only affects DFT bin 0 (handled via constant D0 downstream).
    const int   seg   = (tid < NSEG) ? tid : (NSEG - 1);
    const float valid = (tid < NSEG) ? 1.0f : 0.0f;
    const int   base  = seg * 64;

    float zr[64], zi[64];
#pragma unroll
    for (int i = 0; i < 64; ++i) {
        const int rb = br6(i);
        zr[i] = xl[swzA(base + 2 * rb)];
        zi[i] = xl[swzA(base + 2 * rb + 1)];
    }

    constexpr float STR[6] = {-1.0f, 0.0f, 0.70710678f, 0.92387953f, 0.98078528f, 0.99518473f};
    constexpr float STI[6] = {0.0f, -1.0f, -0.70710678f, -0.38268343f, -0.19509032f, -0.09801714f};
#pragma unroll
    for (int st = 0; st < 6; ++st) {
        const int m = 1 << st;
        float wr = 1.0f, wi = 0.0f;
#pragma unroll
        for (int j = 0; j < m; ++j) {
#pragma unroll
            for (int k = 0; k < 64; k += 2 * m) {
                const int a = k + j, b = a + m;
                float tr = wr * zr[b] - wi * zi[b];
                float ti = wr * zi[b] + wi * zr[b];
                zr[b] = zr[a] - tr; zi[b] = zi[a] - ti;
                zr[a] += tr;        zi[a] += ti;
            }
            float nwr = wr * STR[st] - wi * STI[st];
            wi = wr * STI[st] + wi * STR[st];
            wr = nwr;
        }
    }

    float vals[64];
    float p64;
    const float INV128 = 1.0f / 128.0f;
    {
        float v0 = zr[0] + zi[0];
        vals[0] = v0 * v0 * INV128 * valid;
        float v1 = zr[0] - zi[0];
        p64 = v1 * v1 * INV128 * valid;
        vals[32] = (zr[32] * zr[32] + zi[32] * zi[32]) * (2.0f * INV128) * valid;
    }
    float Wr = 0.9987954562f, Wi = -0.0490676743f;
#pragma unroll
    for (int k = 1; k < 32; ++k) {
        float ar = 0.5f * (zr[k] + zr[64 - k]);
        float ai = 0.5f * (zi[k] - zi[64 - k]);
        float br_ = 0.5f * (zi[k] + zi[64 - k]);
        float bi_ = 0.5f * (zr[64 - k] - zr[k]);
        float tr = Wr * br_ - Wi * bi_;
        float ti = Wr * bi_ + Wi * br_;
        float e1r = ar + tr, e1i = ai + ti;
        float e2r = ar - tr, e2i = ai - ti;
        vals[k]      = (e1r * e1r + e1i * e1i) * (2.0f * INV128) * valid;
        vals[64 - k] = (e2r * e2r + e2i * e2i) * (2.0f * INV128) * valid;
        float nWr = Wr * 0.9987954562f - Wi * (-0.0490676743f);
        Wi = Wr * (-0.0490676743f) + Wi * 0.9987954562f;
        Wr = nWr;
    }

    // Butterfly transpose-reduce across the wave (63 shfls; static slots).
    const int l = lane;
#define RSTAGE(m)                                                    \
    {                                                                \
        const bool hi = (l & (m)) != 0;                              \
        _Pragma("unroll")                                            \
        for (int j = 0; j < (m); ++j) {                              \
            float a = vals[j], b = vals[j + (m)];                    \
            float t = __shfl_xor(hi ? a : b, (m));                   \
            vals[j] = (hi ? b : a) + t;                              \
        }                                                            \
    }
    RSTAGE(32) RSTAGE(16) RSTAGE(8) RSTAGE(4) RSTAGE(2) RSTAGE(1)
#undef RSTAGE
    p64 += __shfl_xor(p64, 32);
    p64 += __shfl_xor(p64, 16);
    p64 += __shfl_xor(p64, 8);
    p64 += __shfl_xor(p64, 4);
    p64 += __shfl_xor(p64, 2);
    p64 += __shfl_xor(p64, 1);

    // Cross-wave reduce in LDS (reuse xl: all xl reads are done). One block
    // owns one channel, so plain stores suffice -> no memset dispatch, no
    // global atomics.
    __syncthreads();
    float* red = xl;
    red[w * 80 + lane] = vals[0];
    if (lane == 0) red[320 + w] = p64;
    __syncthreads();
    if (tid < NF) {
        float s;
        if (tid < 64) s = red[tid] + red[80 + tid] + red[160 + tid] + red[240 + tid];
        else          s = red[320] + red[321] + red[322] + red[323];
        psd_g[ch * NF + tid] = s;
    }
}

// ---------------- Kernel B1: sqrt(psd) + barycenter sum over b ----------------
__launch_bounds__(256)
__global__ void sqrtp_kernel(const float* __restrict__ psd_g, float* __restrict__ sqrtP,
                             float* __restrict__ S) {
    int id = blockIdx.x * 256 + threadIdx.x;
    if (id >= 64 * NF) return;
    int c = id / NF, f = id - c * NF;
    float sum = 0.0f;
    for (int b = 0; b < 32; ++b) {
        int ch = (b << 6) + c;
        float sp = sqrtf(psd_g[ch * NF + f] * (1.0f / 255.0f));   // mean over 255 segs
        sqrtP[ch * NF + f] = sp;
        sum += sp;
    }
    S[id] = sum * (1.0f / 65.0f);
}

// ---------------- Kernel B2: D -> h (irfft) -> conv-layout filter ----------------
__launch_bounds__(128)
__global__ void filt_kernel(const float* __restrict__ sqrtP, const float* __restrict__ S,
                            float* __restrict__ h2g) {
    __shared__ float Dl[NF];
    const int ch = blockIdx.x;
    const int c  = ch & 63;
    const int n  = threadIdx.x;
    if (n < NF) {
        if (n == 0) {
            // bin 0 of psd is pure rounding noise in the reference; its D ratio
            // concentrates at 32/65 (255-segment averaging) -> pin it.
            Dl[0] = 32.0f / 65.0f;
        } else {
            float sp = sqrtP[ch * NF + n];
            float sv = S[c * NF + n];
            Dl[n] = (sp > 0.0f) ? sv / sp : 0.0f;
        }
    }
    __syncthreads();
    float sum = Dl[0] + ((n & 1) ? -Dl[64] : Dl[64]);
#pragma unroll
    for (int f = 1; f < 64; ++f) {
        int m = (f * n) & 127;
        sum += 2.0f * Dl[f] * cosf((float)m * 0.04908738521f);
    }
    float h = sum * (1.0f / 128.0f);
    // fftshift+flip+correlation collapses (h even) to H2[k] = h[(k-63) mod 128]
    h2g[ch * 128 + ((n + 63) & 127)] = h;
}

// ---------------- Kernel C: depthwise FIR as banded-Toeplitz MFMA GEMM ------
// o[t] = sum_m h2[m] x[t-63+m].  Per 16-output block i, 16 blocks j:
//   D[i][j] = sum_u A[i][u] B[u][j],  A[i][u] = h2[u-i-1] (16x160 banded),
//   B[u][j] = Xl[16j+u],  Xl[u] = x[t0-64+u].
// bf16 hi/lo split of both operands (hi*hi + hi*lo + lo*hi) => f32-accurate.
// A and B fragments use the SAME element->k mapping, so any bijective k
// relabeling is correct; only the C/D layout must match HW (m89-verified):
//   C/D: col = lane&15, row = (lane>>4)*4 + reg
#define BS    4096
#define KPAD  160
#define XU    (BS + KPAD)                       // 4256 staged x values
#define PHYS(u) ((u) + (((u) >> 4) << 2))       // +4 bf16 pad per 16 (bank spread)

__attribute__((amdgpu_flat_work_group_size(256, 256), amdgpu_waves_per_eu(4, 4)))
__global__ void conv_kernel(const float* __restrict__ x, const float* __restrict__ h2g,
                            float* __restrict__ out) {
    __shared__ __align__(16) unsigned short Xh[PHYS(XU)];   // 10640 B
    __shared__ __align__(16) unsigned short Xl[PHYS(XU)];   // 10640 B
    const int bid  = blockIdx.x;
    const int ch   = bid >> 2;
    const int t0   = (bid & 3) * BS;
    const int tid  = threadIdx.x;
    const int lane = tid & 63;
    const int w    = tid >> 6;
    const float* __restrict__ xrow = x + (size_t)ch * TLEN;

    // A-fragments (filter Toeplitz band), built once into 40 VGPRs.
    bf16x8 Ah[5], Al[5];
    {
        const float* __restrict__ hrow = h2g + ch * 128;
        const int r  = lane & 15;
        const int kg = (lane >> 4) << 2;
#pragma unroll
        for (int c = 0; c < 5; ++c) {
#pragma unroll
            for (int e = 0; e < 8; ++e) {
                int idx = 32 * c + kg + (e & 3) + ((e >> 2) << 4) - r - 1;
                float hv = (idx >= 0 && idx < 128) ? hrow[idx] : 0.0f;
                unsigned short hh = f2bf(hv);
                Ah[c][e] = (short)hh;
                Al[c][e] = (short)f2bf(hv - bf2f(hh));
            }
        }
    }

    // Stage Xl (hi/lo bf16) into LDS, padded layout, zero outside [0,TLEN).
    for (int i4 = tid; i4 < XU / 4; i4 += 256) {
        int u0  = i4 << 2;
        int src = t0 - 64 + u0;
        float4 v;
        if (src >= 0 && src + 3 < TLEN) {
            v = *reinterpret_cast<const float4*>(xrow + src);
        } else {
            v.x = (src + 0 >= 0 && src + 0 < TLEN) ? xrow[src + 0] : 0.0f;
            v.y = (src + 1 >= 0 && src + 1 < TLEN) ? xrow[src + 1] : 0.0f;
            v.z = (src + 2 >= 0 && src + 2 < TLEN) ? xrow[src + 2] : 0.0f;
            v.w = (src + 3 >= 0 && src + 3 < TLEN) ? xrow[src + 3] : 0.0f;
        }
        ushort4 hi, lo;
        hi.x = f2bf(v.x); lo.x = f2bf(v.x - bf2f(hi.x));
        hi.y = f2bf(v.y); lo.y = f2bf(v.y - bf2f(hi.y));
        hi.z = f2bf(v.z); lo.z = f2bf(v.z - bf2f(hi.z));
        hi.w = f2bf(v.w); lo.w = f2bf(v.w - bf2f(hi.w));
        int p = PHYS(u0);                        // 4-group stays contiguous
        *reinterpret_cast<ushort4*>(Xh + p) = hi;
        *reinterpret_cast<ushort4*>(Xl + p) = lo;
    }
    __syncthreads();

    // 16 tiles of 256 outputs; wave w does tiles w, w+4, w+8, w+12.
    const int ub0 = 16 * (lane & 15) + ((lane >> 4) << 2);
#pragma unroll
    for (int q = 0; q < 4; ++q) {
        const int tb = 256 * (w + (q << 2));
        f32x4 acc = {0.0f, 0.0f, 0.0f, 0.0f};
#pragma unroll
        for (int c = 0; c < 5; ++c) {
            int p0 = PHYS(ub0 + tb + 32 * c);    // k-half0; half1 at +20 elems
            ushort4 h0 = *reinterpret_cast<const ushort4*>(Xh + p0);
            ushort4 h1 = *reinterpret_cast<const ushort4*>(Xh + p0 + 20);
            ushort4 l0 = *reinterpret_cast<const ushort4*>(Xl + p0);
            ushort4 l1 = *reinterpret_cast<const ushort4*>(Xl + p0 + 20);
            bf16x8 bh = {(short)h0.x, (short)h0.y, (short)h0.z, (short)h0.w,
                         (short)h1.x, (short)h1.y, (short)h1.z, (short)h1.w};
            bf16x8 bl = {(short)l0.x, (short)l0.y, (short)l0.z, (short)l0.w,
                         (short)l1.x, (short)l1.y, (short)l1.z, (short)l1.w};
            acc = __builtin_amdgcn_mfma_f32_16x16x32_bf16(Ah[c], bh, acc, 0, 0, 0);
            acc = __builtin_amdgcn_mfma_f32_16x16x32_bf16(Ah[c], bl, acc, 0, 0, 0);
            acc = __builtin_amdgcn_mfma_f32_16x16x32_bf16(Al[c], bh, acc, 0, 0, 0);
        }
        float* orow = out + (size_t)ch * TLEN + t0 + tb
                    + 16 * (lane & 15) + ((lane >> 4) << 2);
        *reinterpret_cast<float4*>(orow) = make_float4(acc[0], acc[1], acc[2], acc[3]);
    }
}

// ---------------- host launcher ----------------
extern "C" void kernel_launch(void* const* d_in, const int* in_sizes, int n_in,
                              void* d_out, int out_size, void* d_ws, size_t ws_size,
                              hipStream_t stream) {
    (void)in_sizes; (void)n_in; (void)out_size; (void)ws_size;
    const float* x = (const float*)d_in[0];
    float* out = (float*)d_out;
    char* ws = (char*)d_ws;
    float* psd_g = (float*)(ws);                 // 2048*65 f32 = 532480 B
    float* sqrtP = (float*)(ws + 532480);        // 2048*65 f32
    float* S     = (float*)(ws + 1064960);       // 64*65 f32 = 16640 B
    float* h2g   = (float*)(ws + 1081600);       // 2048*128 f32 = 1 MiB

    psd_kernel <<<NCH,     256, 0, stream>>>(x, psd_g);     // plain stores, no memset
    sqrtp_kernel<<<17,     256, 0, stream>>>(psd_g, sqrtP, S);
    filt_kernel<<<NCH,     128, 0, stream>>>(sqrtP, S, h2g);
    conv_kernel<<<NCH * 4, 256, 0, stream>>>(x, h2g, out);
}

// Round 10
// 285.494 us; speedup vs baseline: 1.2214x; 1.0247x over previous
//
#include <hip/hip_runtime.h>
#include <math.h>

#define NCH   2048      // B*C = 32*64
#define TLEN  16384
#define NSEG  255
#define NF    65

typedef __attribute__((ext_vector_type(8))) short bf16x8;
typedef __attribute__((ext_vector_type(4))) float f32x4;

__device__ __forceinline__ unsigned short f2bf(float f) {   // RTNE f32->bf16
    union { float f; unsigned u; } v; v.f = f;
    unsigned r = v.u + 0x7FFF + ((v.u >> 16) & 1);
    return (unsigned short)(r >> 16);
}
__device__ __forceinline__ float bf2f(unsigned short b) {
    union { unsigned u; float f; } v; v.u = ((unsigned)b) << 16;
    return v.f;
}

// ---------------- Kernel A: Welch PSD accumulation ----------------
// element-level XOR swizzle: segment bases are 64-float strided -> without this,
// every per-thread FFT load is a 64-way LDS bank conflict.
__device__ __forceinline__ int swzA(int i) {
    return (i & ~63) | ((i & 63) ^ ((i >> 6) & 31));
}
__host__ __device__ constexpr int br6(int i) {
    return ((i & 1) << 5) | ((i & 2) << 3) | ((i & 4) << 1) |
           ((i & 8) >> 1) | ((i & 16) >> 3) | ((i & 32) >> 5);
}

// waves_per_eu(2,2): pin BOTH min and max (R3: min-only still spilled).
// LDS=64KiB caps residency at 2 blocks/CU anyway, so max=2 costs nothing.
__attribute__((amdgpu_flat_work_group_size(256, 256), amdgpu_waves_per_eu(2, 2)))
__global__ void psd_kernel(const float* __restrict__ x, float* __restrict__ psd_g) {
    __shared__ __align__(16) float xl[TLEN];   // exactly 64 KiB
    const int ch  = blockIdx.x;
    const int tid = threadIdx.x;
    const int lane = tid & 63;
    const int w    = tid >> 6;
    const float4* __restrict__ x4 = reinterpret_cast<const float4*>(x) + (size_t)ch * (TLEN / 4);
    // Staged writes as paired b64: swzA keeps even/odd neighbors adjacent,
    // possibly order-swapped; swap parity = bit0 of the xor mask = (i>>6)&1.
#pragma unroll
    for (int it = 0; it < 16; ++it) {
        int i4 = it * 256 + tid;
        float4 v = x4[i4];
        int i  = i4 << 2;
        int a0 = swzA(i);
        const bool sw = ((i >> 6) & 1) != 0;
        float2 p0 = sw ? make_float2(v.y, v.x) : make_float2(v.x, v.y);
        float2 p1 = sw ? make_float2(v.w, v.z) : make_float2(v.z, v.w);
        *reinterpret_cast<float2*>(&xl[a0 & ~1])       = p0;
        *reinterpret_cast<float2*>(&xl[(a0 ^ 2) & ~1]) = p1;
    }
    __syncthreads();

    // one thread = one 128-sample segment (50% overlap). Per-segment mean
    // subtraction only affects DFT bin 0 (handled via constant D0 downstream).
    const int   seg   = (tid < NSEG) ? tid : (NSEG - 1);
    const float valid = (tid < NSEG) ? 1.0f : 0.0f;
    const int   base  = seg * 64;

    // pack reals into 64 complex, bit-reversed; paired b64 reads.
    // swap parity = (seg + bit5(rb))&1 = (seg ^ i)&1  [br6: bit5(rb)=bit0(i)]
    float zr[64], zi[64];
#pragma unroll
    for (int i = 0; i < 64; ++i) {
        const int rb = br6(i);
        int a = swzA(base + 2 * rb);
        const float2 v = *reinterpret_cast<const float2*>(&xl[a & ~1]);
        const bool sw = ((seg ^ i) & 1) != 0;
        zr[i] = sw ? v.y : v.x;
        zi[i] = sw ? v.x : v.y;
    }

    constexpr float STR[6] = {-1.0f, 0.0f, 0.70710678f, 0.92387953f, 0.98078528f, 0.99518473f};
    constexpr float STI[6] = {0.0f, -1.0f, -0.70710678f, -0.38268343f, -0.19509032f, -0.09801714f};
#pragma unroll
    for (int st = 0; st < 6; ++st) {
        const int m = 1 << st;
        float wr = 1.0f, wi = 0.0f;
#pragma unroll
        for (int j = 0; j < m; ++j) {
#pragma unroll
            for (int k = 0; k < 64; k += 2 * m) {
                const int a = k + j, b = a + m;
                float tr = wr * zr[b] - wi * zi[b];
                float ti = wr * zi[b] + wi * zr[b];
                zr[b] = zr[a] - tr; zi[b] = zi[a] - ti;
                zr[a] += tr;        zi[a] += ti;
            }
            float nwr = wr * STR[st] - wi * STI[st];
            wi = wr * STI[st] + wi * STR[st];
            wr = nwr;
        }
    }

    float vals[64];
    float p64;
    const float INV128 = 1.0f / 128.0f;
    {
        float v0 = zr[0] + zi[0];
        vals[0] = v0 * v0 * INV128 * valid;
        float v1 = zr[0] - zi[0];
        p64 = v1 * v1 * INV128 * valid;
        vals[32] = (zr[32] * zr[32] + zi[32] * zi[32]) * (2.0f * INV128) * valid;
    }
    float Wr = 0.9987954562f, Wi = -0.0490676743f;
#pragma unroll
    for (int k = 1; k < 32; ++k) {
        float ar = 0.5f * (zr[k] + zr[64 - k]);
        float ai = 0.5f * (zi[k] - zi[64 - k]);
        float br_ = 0.5f * (zi[k] + zi[64 - k]);
        float bi_ = 0.5f * (zr[64 - k] - zr[k]);
        float tr = Wr * br_ - Wi * bi_;
        float ti = Wr * bi_ + Wi * br_;
        float e1r = ar + tr, e1i = ai + ti;
        float e2r = ar - tr, e2i = ai - ti;
        vals[k]      = (e1r * e1r + e1i * e1i) * (2.0f * INV128) * valid;
        vals[64 - k] = (e2r * e2r + e2i * e2i) * (2.0f * INV128) * valid;
        float nWr = Wr * 0.9987954562f - Wi * (-0.0490676743f);
        Wi = Wr * (-0.0490676743f) + Wi * 0.9987954562f;
        Wr = nWr;
    }

    // Butterfly transpose-reduce across the wave (63 shfls; static slots).
    const int l = lane;
#define RSTAGE(m)                                                    \
    {                                                                \
        const bool hi = (l & (m)) != 0;                              \
        _Pragma("unroll")                                            \
        for (int j = 0; j < (m); ++j) {                              \
            float a = vals[j], b = vals[j + (m)];                    \
            float t = __shfl_xor(hi ? a : b, (m));                   \
            vals[j] = (hi ? b : a) + t;                              \
        }                                                            \
    }
    RSTAGE(32) RSTAGE(16) RSTAGE(8) RSTAGE(4) RSTAGE(2) RSTAGE(1)
#undef RSTAGE
    p64 += __shfl_xor(p64, 32);
    p64 += __shfl_xor(p64, 16);
    p64 += __shfl_xor(p64, 8);
    p64 += __shfl_xor(p64, 4);
    p64 += __shfl_xor(p64, 2);
    p64 += __shfl_xor(p64, 1);

    // Cross-wave reduce in LDS (xl reads done). Plain stores, no atomics.
    __syncthreads();
    float* red = xl;
    red[w * 80 + lane] = vals[0];
    if (lane == 0) red[320 + w] = p64;
    __syncthreads();
    if (tid < NF) {
        float s;
        if (tid < 64) s = red[tid] + red[80 + tid] + red[160 + tid] + red[240 + tid];
        else          s = red[320] + red[321] + red[322] + red[323];
        psd_g[ch * NF + tid] = s;
    }
}

// ---- Kernel B (fused): barycenter + D -> h (irfft) -> conv-layout filter ----
// Each block (one channel) recomputes its column's barycenter directly from
// psd_g (32 extra sqrt per bin, all L2 hits) -> drops the sqrtp dispatch and
// the sqrtP/S buffers. Cosine table built once in LDS (1 cosf/thread) instead
// of 63 libm cosf per thread.
__launch_bounds__(128)
__global__ void filt_kernel(const float* __restrict__ psd_g, float* __restrict__ h2g) {
    __shared__ float Dl[NF];
    __shared__ float cosT[128];
    const int ch = blockIdx.x;
    const int c  = ch & 63;
    const int n  = threadIdx.x;
    cosT[n] = cosf((float)n * 0.04908738521f);     // 2*pi/128
    if (n < NF) {
        if (n == 0) {
            // bin 0 of psd is pure rounding noise in the reference; its D ratio
            // concentrates at 32/65 (255-segment averaging) -> pin it.
            Dl[0] = 32.0f / 65.0f;
        } else {
            float sp = sqrtf(psd_g[ch * NF + n] * (1.0f / 255.0f));
            float s = 0.0f;
            for (int b = 0; b < 32; ++b)
                s += sqrtf(psd_g[((b << 6) + c) * NF + n] * (1.0f / 255.0f));
            s *= (1.0f / 65.0f);
            Dl[n] = (sp > 0.0f) ? s / sp : 0.0f;
        }
    }
    __syncthreads();
    // h[n] = (1/128)(D0 + 2*sum_{f=1..63} Df cos(2pi f n/128) + D64*(-1)^n)
    float sum = Dl[0] + ((n & 1) ? -Dl[64] : Dl[64]);
#pragma unroll
    for (int f = 1; f < 64; ++f) {
        sum += 2.0f * Dl[f] * cosT[(f * n) & 127];
    }
    float h = sum * (1.0f / 128.0f);
    // fftshift+flip+correlation collapses (h even) to H2[k] = h[(k-63) mod 128]
    h2g[ch * 128 + ((n + 63) & 127)] = h;
}

// ---------------- Kernel C: depthwise FIR as banded-Toeplitz MFMA GEMM ------
// o[t] = sum_m h2[m] x[t-63+m].  Per 16-output block i, 16 blocks j:
//   D[i][j] = sum_u A[i][u] B[u][j],  A[i][u] = h2[u-i-1] (16x160 banded),
//   B[u][j] = Xl[16j+u],  Xl[u] = x[t0-64+u].
// bf16 hi/lo split of both operands (hi*hi + hi*lo + lo*hi) => f32-accurate.
// A and B fragments use the SAME element->k mapping, so any bijective k
// relabeling is correct; only the C/D layout must match HW (m89-verified):
//   C/D: col = lane&15, row = (lane>>4)*4 + reg
#define BS    4096
#define KPAD  160
#define XU    (BS + KPAD)                       // 4256 staged x values
#define PHYS(u) ((u) + (((u) >> 4) << 2))       // +4 bf16 pad per 16 (bank spread)

__attribute__((amdgpu_flat_work_group_size(256, 256), amdgpu_waves_per_eu(4, 4)))
__global__ void conv_kernel(const float* __restrict__ x, const float* __restrict__ h2g,
                            float* __restrict__ out) {
    __shared__ __align__(16) unsigned short Xh[PHYS(XU)];   // 10640 B
    __shared__ __align__(16) unsigned short Xl[PHYS(XU)];   // 10640 B
    const int bid  = blockIdx.x;
    const int ch   = bid >> 2;
    const int t0   = (bid & 3) * BS;
    const int tid  = threadIdx.x;
    const int lane = tid & 63;
    const int w    = tid >> 6;
    const float* __restrict__ xrow = x + (size_t)ch * TLEN;

    // A-fragments (filter Toeplitz band), built once into 40 VGPRs.
    bf16x8 Ah[5], Al[5];
    {
        const float* __restrict__ hrow = h2g + ch * 128;
        const int r  = lane & 15;
        const int kg = (lane >> 4) << 2;
#pragma unroll
        for (int c = 0; c < 5; ++c) {
#pragma unroll
            for (int e = 0; e < 8; ++e) {
                int idx = 32 * c + kg + (e & 3) + ((e >> 2) << 4) - r - 1;
                float hv = (idx >= 0 && idx < 128) ? hrow[idx] : 0.0f;
                unsigned short hh = f2bf(hv);
                Ah[c][e] = (short)hh;
                Al[c][e] = (short)f2bf(hv - bf2f(hh));
            }
        }
    }

    // Stage Xl (hi/lo bf16) into LDS, padded layout, zero outside [0,TLEN).
    for (int i4 = tid; i4 < XU / 4; i4 += 256) {
        int u0  = i4 << 2;
        int src = t0 - 64 + u0;
        float4 v;
        if (src >= 0 && src + 3 < TLEN) {
            v = *reinterpret_cast<const float4*>(xrow + src);
        } else {
            v.x = (src + 0 >= 0 && src + 0 < TLEN) ? xrow[src + 0] : 0.0f;
            v.y = (src + 1 >= 0 && src + 1 < TLEN) ? xrow[src + 1] : 0.0f;
            v.z = (src + 2 >= 0 && src + 2 < TLEN) ? xrow[src + 2] : 0.0f;
            v.w = (src + 3 >= 0 && src + 3 < TLEN) ? xrow[src + 3] : 0.0f;
        }
        ushort4 hi, lo;
        hi.x = f2bf(v.x); lo.x = f2bf(v.x - bf2f(hi.x));
        hi.y = f2bf(v.y); lo.y = f2bf(v.y - bf2f(hi.y));
        hi.z = f2bf(v.z); lo.z = f2bf(v.z - bf2f(hi.z));
        hi.w = f2bf(v.w); lo.w = f2bf(v.w - bf2f(hi.w));
        int p = PHYS(u0);                        // 4-group stays contiguous
        *reinterpret_cast<ushort4*>(Xh + p) = hi;
        *reinterpret_cast<ushort4*>(Xl + p) = lo;
    }
    __syncthreads();

    // 16 tiles of 256 outputs; wave w does tiles w, w+4, w+8, w+12.
    const int ub0 = 16 * (lane & 15) + ((lane >> 4) << 2);
#pragma unroll
    for (int q = 0; q < 4; ++q) {
        const int tb = 256 * (w + (q << 2));
        f32x4 acc = {0.0f, 0.0f, 0.0f, 0.0f};
#pragma unroll
        for (int c = 0; c < 5; ++c) {
            int p0 = PHYS(ub0 + tb + 32 * c);    // k-half0; half1 at +20 elems
            ushort4 h0 = *reinterpret_cast<const ushort4*>(Xh + p0);
            ushort4 h1 = *reinterpret_cast<const ushort4*>(Xh + p0 + 20);
            ushort4 l0 = *reinterpret_cast<const ushort4*>(Xl + p0);
            ushort4 l1 = *reinterpret_cast<const ushort4*>(Xl + p0 + 20);
            bf16x8 bh = {(short)h0.x, (short)h0.y, (short)h0.z, (short)h0.w,
                         (short)h1.x, (short)h1.y, (short)h1.z, (short)h1.w};
            bf16x8 bl = {(short)l0.x, (short)l0.y, (short)l0.z, (short)l0.w,
                         (short)l1.x, (short)l1.y, (short)l1.z, (short)l1.w};
            acc = __builtin_amdgcn_mfma_f32_16x16x32_bf16(Ah[c], bh, acc, 0, 0, 0);
            acc = __builtin_amdgcn_mfma_f32_16x16x32_bf16(Ah[c], bl, acc, 0, 0, 0);
            acc = __builtin_amdgcn_mfma_f32_16x16x32_bf16(Al[c], bh, acc, 0, 0, 0);
        }
        float* orow = out + (size_t)ch * TLEN + t0 + tb
                    + 16 * (lane & 15) + ((lane >> 4) << 2);
        *reinterpret_cast<float4*>(orow) = make_float4(acc[0], acc[1], acc[2], acc[3]);
    }
}

// ---------------- host launcher ----------------
extern "C" void kernel_launch(void* const* d_in, const int* in_sizes, int n_in,
                              void* d_out, int out_size, void* d_ws, size_t ws_size,
                              hipStream_t stream) {
    (void)in_sizes; (void)n_in; (void)out_size; (void)ws_size;
    const float* x = (const float*)d_in[0];
    float* out = (float*)d_out;
    char* ws = (char*)d_ws;
    float* psd_g = (float*)(ws);                 // 2048*65 f32 = 532480 B
    float* h2g   = (float*)(ws + 532480);        // 2048*128 f32 = 1 MiB

    psd_kernel <<<NCH,     256, 0, stream>>>(x, psd_g);
    filt_kernel<<<NCH,     128, 0, stream>>>(psd_g, h2g);
    conv_kernel<<<NCH * 4, 256, 0, stream>>>(x, h2g, out);
}